// Round 6
// baseline (782.543 us; speedup 1.0000x reference)
//
#include <hip/hip_runtime.h>
#include <hip/hip_bf16.h>
#include <hip/hip_fp16.h>

#define NN 50000
#define NE 800000
#define MP 50048            // NN padded to multiple of 64
#define SCAN_NB 196         // ceil(NN/256)

typedef __bf16 bf16x8 __attribute__((ext_vector_type(8)));
typedef float f32x4 __attribute__((ext_vector_type(4)));

static __device__ __forceinline__ float b2f(unsigned short u) {
  union { unsigned int i; float f; } v; v.i = ((unsigned int)u) << 16; return v.f;
}
static __device__ __forceinline__ unsigned short f2b(float f) {
  __hip_bfloat16 h = __float2bfloat16(f);
  union { __hip_bfloat16 h; unsigned short u; } v; v.h = h; return v.u;
}

// ---------------- edge_index width detection ----------------
__global__ __launch_bounds__(64) void detect_idx(const int* __restrict__ ei, int* flag) {
  __shared__ int nz;
  if (threadIdx.x == 0) nz = 0;
  __syncthreads();
  if (ei[2 * threadIdx.x + 1] != 0) atomicAdd(&nz, 1);
  __syncthreads();
  if (threadIdx.x == 0) *flag = (nz == 0) ? 1 : 0;   // 1 => int64 layout
}

static __device__ __forceinline__ int get_src(const int* ei, int f, int i) {
  return f ? ei[2 * i] : ei[i];
}
static __device__ __forceinline__ int get_dst(const int* ei, int f, int i) {
  return f ? ei[2 * (NE + i)] : ei[NE + i];
}

// ---------------- graph preprocessing ----------------
// dc[i]: high 32 = edge count, low 32 = fixed-point (2^-20) weighted degree
__global__ __launch_bounds__(256) void prep_init(unsigned long long* dc, int n) {
  int i = blockIdx.x * 256 + threadIdx.x;
  if (i < n) dc[i] = 1048576ull;   // self-loop weight 1.0, cnt 0
}

__global__ __launch_bounds__(256) void prep_hist(const int* __restrict__ ei,
    const int* __restrict__ flag, const float* __restrict__ ew,
    unsigned long long* dc, int e) {
  int i = blockIdx.x * 256 + threadIdx.x;
  if (i < e) {
    int f = *flag;
    int d = get_dst(ei, f, i);
    unsigned long long fx = (unsigned long long)(ew[i] * 1048576.0f + 0.5f);
    atomicAdd(&dc[d], (1ull << 32) | fx);
  }
}

__global__ __launch_bounds__(256) void prep_dis(const unsigned long long* __restrict__ dc,
    float* dis, int* cnt, int* cursor, int n) {
  int i = blockIdx.x * 256 + threadIdx.x;
  if (i < n) {
    unsigned long long v = dc[i];
    float d = (float)(unsigned int)(v & 0xffffffffull) * (1.0f / 1048576.0f);
    dis[i] = (d > 0.f) ? rsqrtf(d) : 0.f;
    cnt[i] = (int)(v >> 32);
    cursor[i] = 0;
  }
}

// ---- 3-kernel scan: block partials -> tops scan -> apply ----
__global__ __launch_bounds__(256) void scan_part(const int* __restrict__ cnt,
    int* __restrict__ part, int n) {
  __shared__ int sb[256];
  int t = threadIdx.x, i = blockIdx.x * 256 + t;
  sb[t] = (i < n) ? cnt[i] : 0;
  __syncthreads();
  for (int off = 128; off > 0; off >>= 1) {
    if (t < off) sb[t] += sb[t + off];
    __syncthreads();
  }
  if (t == 0) part[blockIdx.x] = sb[0];
}

__global__ __launch_bounds__(256) void scan_tops(const int* __restrict__ part,
    int* __restrict__ partoff, int* __restrict__ rowstart, int n, int e, int nb) {
  __shared__ int sb[256];
  int t = threadIdx.x;
  int v = (t < nb) ? part[t] : 0;
  sb[t] = v;
  __syncthreads();
  for (int off = 1; off < 256; off <<= 1) {
    int x = (t >= off) ? sb[t - off] : 0;
    __syncthreads();
    sb[t] += x;
    __syncthreads();
  }
  if (t < nb) partoff[t] = sb[t] - v;   // exclusive block offsets
  if (t == 0) rowstart[n] = e;
}

__global__ __launch_bounds__(256) void scan_apply(const int* __restrict__ cnt,
    const int* __restrict__ partoff, int* __restrict__ rowstart, int n) {
  __shared__ int sb[256];
  int t = threadIdx.x, i = blockIdx.x * 256 + t;
  int v = (i < n) ? cnt[i] : 0;
  sb[t] = v;
  __syncthreads();
  for (int off = 1; off < 256; off <<= 1) {
    int x = (t >= off) ? sb[t - off] : 0;
    __syncthreads();
    sb[t] += x;
    __syncthreads();
  }
  if (i < n) rowstart[i] = partoff[blockIdx.x] + sb[t] - v;
}

// packed edge record: .x = src node, .y = bit-cast norm weight
__global__ __launch_bounds__(256) void prep_scatter(const int* __restrict__ ei,
    const int* __restrict__ flag, const float* __restrict__ ew,
    const float* __restrict__ dis, const int* __restrict__ rowstart,
    int* __restrict__ cursor, int2* __restrict__ epack, int e) {
  int i = blockIdx.x * 256 + threadIdx.x;
  if (i >= e) return;
  int f = *flag;
  int d = get_dst(ei, f, i);
  int s = get_src(ei, f, i);
  int pos = rowstart[d] + atomicAdd(&cursor[d], 1);
  float nm = dis[s] * ew[i] * dis[d];
  epack[pos] = make_int2(s, __float_as_int(nm));
}

// ---------------- input conversions (once) ----------------
__global__ __launch_bounds__(256) void cvt_x(const float* __restrict__ x,
    unsigned short* __restrict__ Hh, unsigned short* __restrict__ Hl,
    int total, int valid) {
  int i = blockIdx.x * 256 + threadIdx.x;
  int b = i * 4;
  if (b >= total) return;
  ushort4 oh, ol;
  float v0 = (b + 0 < valid) ? x[b + 0] : 0.f;
  float v1 = (b + 1 < valid) ? x[b + 1] : 0.f;
  float v2 = (b + 2 < valid) ? x[b + 2] : 0.f;
  float v3 = (b + 3 < valid) ? x[b + 3] : 0.f;
  oh.x = f2b(v0); ol.x = f2b(v0 - b2f(oh.x));
  oh.y = f2b(v1); ol.y = f2b(v1 - b2f(oh.y));
  oh.z = f2b(v2); ol.z = f2b(v2 - b2f(oh.z));
  oh.w = f2b(v3); ol.w = f2b(v3 - b2f(oh.w));
  *(ushort4*)(Hh + b) = oh;
  *(ushort4*)(Hl + b) = ol;
}

// weights [k][n] 128x128 fp32 (7 layers) -> transposed [n][k] hi/lo bf16
__global__ __launch_bounds__(256) void cvt_w(const float* __restrict__ W1,
    const float* __restrict__ Wm, unsigned short* __restrict__ Wth,
    unsigned short* __restrict__ Wtl) {
  int i = blockIdx.x * 256 + threadIdx.x;           // 7*16384
  if (i >= 7 * 16384) return;
  int l = i >> 14, r = i & 16383;
  int k = r >> 7, n = r & 127;
  const float* src = (l == 0) ? W1 : (Wm + (size_t)(l - 1) * 16384);
  float v = src[k * 128 + n];
  unsigned short h = f2b(v);
  int o = l * 16384 + n * 128 + k;
  Wth[o] = h;
  Wtl[o] = f2b(v - b2f(h));
}

// ---------------- MFMA split-bf16 GEMM: XW[MP,128] (fp16) = H @ W ----------------
__global__ __launch_bounds__(256) void gemm_mfma(
    const unsigned short* __restrict__ Hh, const unsigned short* __restrict__ Hl,
    const unsigned short* __restrict__ Bh, const unsigned short* __restrict__ Bl,
    __half* __restrict__ XW) {
  __shared__ float C[64][133];
  int t = threadIdx.x;
  int lane = t & 63, wv = t >> 6;
  int m16 = lane & 15, quad = lane >> 4;
  int rowbase = blockIdx.x * 64;
  int arow = rowbase + wv * 16 + m16;
  f32x4 acc[8];
#pragma unroll
  for (int i = 0; i < 8; ++i) acc[i] = (f32x4){0.f, 0.f, 0.f, 0.f};
  const unsigned short* ph = Hh + (size_t)arow * 128 + quad * 8;
  const unsigned short* pl = Hl + (size_t)arow * 128 + quad * 8;
#pragma unroll
  for (int kc = 0; kc < 4; ++kc) {
    bf16x8 ah = *(const bf16x8*)(ph + kc * 32);
    bf16x8 al = *(const bf16x8*)(pl + kc * 32);
    int k0 = kc * 32 + quad * 8;
#pragma unroll
    for (int tt = 0; tt < 8; ++tt) {
      int nn = tt * 16 + m16;
      bf16x8 bh = *(const bf16x8*)(Bh + nn * 128 + k0);
      bf16x8 bl = *(const bf16x8*)(Bl + nn * 128 + k0);
      acc[tt] = __builtin_amdgcn_mfma_f32_16x16x32_bf16(ah, bh, acc[tt], 0, 0, 0);
      acc[tt] = __builtin_amdgcn_mfma_f32_16x16x32_bf16(ah, bl, acc[tt], 0, 0, 0);
      acc[tt] = __builtin_amdgcn_mfma_f32_16x16x32_bf16(al, bh, acc[tt], 0, 0, 0);
    }
  }
#pragma unroll
  for (int tt = 0; tt < 8; ++tt)
#pragma unroll
    for (int r = 0; r < 4; ++r)
      C[wv * 16 + quad * 4 + r][tt * 16 + m16] = acc[tt][r];
  __syncthreads();
  int rr = t >> 2;               // 0..63
  int cb = (t & 3) * 32;         // col base
  const float* crow = &C[rr][cb];
  __half2 o[16];
#pragma unroll
  for (int i = 0; i < 16; ++i) {
    __half2 h;
    h.x = __float2half_rn(crow[2 * i]);
    h.y = __float2half_rn(crow[2 * i + 1]);
    o[i] = h;
  }
  uint4* dst = (uint4*)(XW + (size_t)(rowbase + rr) * 128 + cb);
  dst[0] = ((const uint4*)o)[0];
  dst[1] = ((const uint4*)o)[1];
  dst[2] = ((const uint4*)o)[2];
  dst[3] = ((const uint4*)o)[3];
}

// ---------------- CSR aggregation + bias + relu -> bf16 hi/lo H ----------------
// one wave per node; 8-deep edge unroll, 8 independent accumulator pairs
__global__ __launch_bounds__(256) void agg_csr(const __half* __restrict__ XW,
    const int* __restrict__ rowstart, const int2* __restrict__ epack,
    const float* __restrict__ dis, const float* __restrict__ bias,
    unsigned short* __restrict__ Hh, unsigned short* __restrict__ Hl, int n) {
  int w = (blockIdx.x * 256 + threadIdx.x) >> 6;
  int l = threadIdx.x & 63;
  if (w >= n) return;
  float dd = dis[w];
  float d2 = dd * dd;
  __half2 sh = ((const __half2*)(XW + (size_t)w * 128))[l];
  float2 A[8];
  A[0] = make_float2(d2 * __low2float(sh), d2 * __high2float(sh));
#pragma unroll
  for (int i = 1; i < 8; ++i) A[i] = make_float2(0.f, 0.f);
  int p = rowstart[w], p1 = rowstart[w + 1];
  for (; p + 8 <= p1; p += 8) {
    int2 e[8];
#pragma unroll
    for (int i = 0; i < 8; ++i) e[i] = epack[p + i];
    __half2 r[8];
#pragma unroll
    for (int i = 0; i < 8; ++i)
      r[i] = ((const __half2*)(XW + (size_t)e[i].x * 128))[l];
#pragma unroll
    for (int i = 0; i < 8; ++i) {
      float wt = __int_as_float(e[i].y);
      A[i].x = fmaf(wt, __low2float(r[i]), A[i].x);
      A[i].y = fmaf(wt, __high2float(r[i]), A[i].y);
    }
  }
  for (; p < p1; ++p) {
    int2 e0 = epack[p];
    float wt = __int_as_float(e0.y);
    __half2 r0 = ((const __half2*)(XW + (size_t)e0.x * 128))[l];
    A[0].x = fmaf(wt, __low2float(r0), A[0].x);
    A[0].y = fmaf(wt, __high2float(r0), A[0].y);
  }
  float2 b = ((const float2*)bias)[l];
  float vx = fmaxf(A[0].x + A[1].x + A[2].x + A[3].x + A[4].x + A[5].x + A[6].x + A[7].x + b.x, 0.f);
  float vy = fmaxf(A[0].y + A[1].y + A[2].y + A[3].y + A[4].y + A[5].y + A[6].y + A[7].y + b.y, 0.f);
  ushort2 oh, ol;
  oh.x = f2b(vx); ol.x = f2b(vx - b2f(oh.x));
  oh.y = f2b(vy); ol.y = f2b(vy - b2f(oh.y));
  ((ushort2*)(Hh + (size_t)w * 128))[l] = oh;
  ((ushort2*)(Hl + (size_t)w * 128))[l] = ol;
}

// ---------------- final layer ----------------
__global__ __launch_bounds__(256) void gemm_w8(const unsigned short* __restrict__ Hh,
    const unsigned short* __restrict__ Hl, const float* __restrict__ W8,
    float* __restrict__ XW2, int n) {
  __shared__ float w[256];
  int t = threadIdx.x;
  w[t] = W8[t];
  __syncthreads();
  int r = blockIdx.x * 256 + t;
  if (r >= n) return;
  const unsigned short* hh = Hh + (size_t)r * 128;
  const unsigned short* hl = Hl + (size_t)r * 128;
  float a0 = 0.f, a1 = 0.f;
#pragma unroll
  for (int k = 0; k < 128; k += 4) {
    ushort4 uh = *(const ushort4*)(hh + k);
    ushort4 ul = *(const ushort4*)(hl + k);
    float h0 = b2f(uh.x) + b2f(ul.x);
    float h1 = b2f(uh.y) + b2f(ul.y);
    float h2 = b2f(uh.z) + b2f(ul.z);
    float h3 = b2f(uh.w) + b2f(ul.w);
    a0 += h0 * w[2 * k + 0] + h1 * w[2 * k + 2] + h2 * w[2 * k + 4] + h3 * w[2 * k + 6];
    a1 += h0 * w[2 * k + 1] + h1 * w[2 * k + 3] + h2 * w[2 * k + 5] + h3 * w[2 * k + 7];
  }
  XW2[r * 2 + 0] = a0;
  XW2[r * 2 + 1] = a1;
}

__global__ __launch_bounds__(256) void agg_final(const float* __restrict__ XW2,
    const int* __restrict__ rowstart, const int2* __restrict__ epack,
    const float* __restrict__ dis, const float* __restrict__ b8,
    float* __restrict__ out, int n) {
  int i = blockIdx.x * 256 + threadIdx.x;
  if (i >= n) return;
  float d = dis[i], d2 = d * d;
  float a0 = d2 * XW2[i * 2 + 0];
  float a1 = d2 * XW2[i * 2 + 1];
  int p1 = rowstart[i + 1];
  for (int p = rowstart[i]; p < p1; ++p) {
    int2 e0 = epack[p];
    float wt = __int_as_float(e0.y);
    a0 = fmaf(wt, XW2[e0.x * 2 + 0], a0);
    a1 = fmaf(wt, XW2[e0.x * 2 + 1], a1);
  }
  out[i * 2 + 0] = a0 + b8[0];
  out[i * 2 + 1] = a1 + b8[1];
}

// ---------------- launcher ----------------
static inline char* alignp(char* p) {
  return (char*)(((uintptr_t)p + 255) & ~(uintptr_t)255);
}

extern "C" void kernel_launch(void* const* d_in, const int* in_sizes, int n_in,
                              void* d_out, int out_size, void* d_ws, size_t ws_size,
                              hipStream_t stream) {
  (void)in_sizes; (void)n_in; (void)out_size; (void)ws_size;
  const int n = NN, e = NE;
  const float* x  = (const float*)d_in[0];
  const int*   ei = (const int*)d_in[1];
  const float* ea = (const float*)d_in[2];
  const float* W1 = (const float*)d_in[3];
  const float* b1 = (const float*)d_in[4];
  const float* Wm = (const float*)d_in[5];
  const float* bm = (const float*)d_in[6];
  const float* W8 = (const float*)d_in[7];
  const float* b8 = (const float*)d_in[8];
  float* out = (float*)d_out;

  char* w = (char*)d_ws;
  int*   flag   = (int*)w;            w = alignp(w + 4);
  int*   part   = (int*)w;            w = alignp(w + SCAN_NB * 4);
  int*   partoff= (int*)w;            w = alignp(w + SCAN_NB * 4);
  unsigned long long* dc = (unsigned long long*)w; w = alignp(w + (size_t)n * 8);
  float* dis    = (float*)w;          w = alignp(w + (size_t)n * 4);
  int*   cnt    = (int*)w;            w = alignp(w + (size_t)n * 4);
  int*   cursor = (int*)w;            w = alignp(w + (size_t)n * 4);
  int*   rowst  = (int*)w;            w = alignp(w + (size_t)(n + 1) * 4);
  int2*  epack  = (int2*)w;           w = alignp(w + (size_t)e * 8);
  unsigned short* Hh  = (unsigned short*)w;  w = alignp(w + (size_t)MP * 128 * 2);
  unsigned short* Hl  = (unsigned short*)w;  w = alignp(w + (size_t)MP * 128 * 2);
  unsigned short* Wth = (unsigned short*)w;  w = alignp(w + (size_t)7 * 16384 * 2);
  unsigned short* Wtl = (unsigned short*)w;  w = alignp(w + (size_t)7 * 16384 * 2);
  __half* XW  = (__half*)w;           w = alignp(w + (size_t)MP * 128 * 2);
  float* XW2  = (float*)w;            w = alignp(w + (size_t)MP * 2 * 4);

  const int GN = (n + 255) / 256;
  const int GE = (e + 255) / 256;

  detect_idx<<<1, 64, 0, stream>>>(ei, flag);
  prep_init<<<GN, 256, 0, stream>>>(dc, n);
  prep_hist<<<GE, 256, 0, stream>>>(ei, flag, ea, dc, e);
  prep_dis<<<GN, 256, 0, stream>>>(dc, dis, cnt, cursor, n);
  scan_part<<<SCAN_NB, 256, 0, stream>>>(cnt, part, n);
  scan_tops<<<1, 256, 0, stream>>>(part, partoff, rowst, n, e, SCAN_NB);
  scan_apply<<<SCAN_NB, 256, 0, stream>>>(cnt, partoff, rowst, n);
  prep_scatter<<<GE, 256, 0, stream>>>(ei, flag, ea, dis, rowst, cursor, epack, e);
  cvt_x<<<(MP * 128 / 4 + 255) / 256, 256, 0, stream>>>(x, Hh, Hl, MP * 128, n * 128);
  cvt_w<<<(7 * 16384 + 255) / 256, 256, 0, stream>>>(W1, Wm, Wth, Wtl);

  for (int l = 0; l < 7; ++l) {
    const unsigned short* Bh = Wth + (size_t)l * 16384;
    const unsigned short* Bl = Wtl + (size_t)l * 16384;
    const float* bl = (l == 0) ? b1 : bm + (size_t)(l - 1) * 128;
    gemm_mfma<<<MP / 64, 256, 0, stream>>>(Hh, Hl, Bh, Bl, XW);
    agg_csr<<<(n * 64 + 255) / 256, 256, 0, stream>>>(XW, rowst, epack, dis, bl, Hh, Hl, n);
  }
  gemm_w8<<<GN, 256, 0, stream>>>(Hh, Hl, W8, XW2, n);
  agg_final<<<GN, 256, 0, stream>>>(XW2, rowst, epack, dis, b8, out, n);
}

// Round 7
// 633.059 us; speedup vs baseline: 1.2361x; 1.2361x over previous
//
#include <hip/hip_runtime.h>
#include <hip/hip_bf16.h>
#include <hip/hip_fp16.h>

#define NN 50000
#define NE 800000
#define MP 50048            // NN padded to multiple of 128 (50048 = 391*128)
#define SCAN_NB 196         // ceil(NN/256)

typedef __bf16 bf16x8 __attribute__((ext_vector_type(8)));
typedef float f32x4 __attribute__((ext_vector_type(4)));

static __device__ __forceinline__ float b2f(unsigned short u) {
  union { unsigned int i; float f; } v; v.i = ((unsigned int)u) << 16; return v.f;
}
static __device__ __forceinline__ unsigned short f2b(float f) {
  __hip_bfloat16 h = __float2bfloat16(f);
  union { __hip_bfloat16 h; unsigned short u; } v; v.h = h; return v.u;
}

// ---------------- edge_index width detection ----------------
__global__ __launch_bounds__(64) void detect_idx(const int* __restrict__ ei, int* flag) {
  __shared__ int nz;
  if (threadIdx.x == 0) nz = 0;
  __syncthreads();
  if (ei[2 * threadIdx.x + 1] != 0) atomicAdd(&nz, 1);
  __syncthreads();
  if (threadIdx.x == 0) *flag = (nz == 0) ? 1 : 0;   // 1 => int64 layout
}

static __device__ __forceinline__ int get_src(const int* ei, int f, int i) {
  return f ? ei[2 * i] : ei[i];
}
static __device__ __forceinline__ int get_dst(const int* ei, int f, int i) {
  return f ? ei[2 * (NE + i)] : ei[NE + i];
}

// ---------------- graph preprocessing ----------------
// dc[i]: high 32 = edge count, low 32 = fixed-point (2^-20) weighted degree
__global__ __launch_bounds__(256) void prep_init(unsigned long long* dc, int n) {
  int i = blockIdx.x * 256 + threadIdx.x;
  if (i < n) dc[i] = 1048576ull;   // self-loop weight 1.0, cnt 0
}

__global__ __launch_bounds__(256) void prep_hist(const int* __restrict__ ei,
    const int* __restrict__ flag, const float* __restrict__ ew,
    unsigned long long* dc, int e) {
  int i = blockIdx.x * 256 + threadIdx.x;
  if (i < e) {
    int f = *flag;
    int d = get_dst(ei, f, i);
    unsigned long long fx = (unsigned long long)(ew[i] * 1048576.0f + 0.5f);
    atomicAdd(&dc[d], (1ull << 32) | fx);
  }
}

__global__ __launch_bounds__(256) void prep_dis(const unsigned long long* __restrict__ dc,
    float* dis, int* cnt, int* cursor, int n) {
  int i = blockIdx.x * 256 + threadIdx.x;
  if (i < n) {
    unsigned long long v = dc[i];
    float d = (float)(unsigned int)(v & 0xffffffffull) * (1.0f / 1048576.0f);
    dis[i] = (d > 0.f) ? rsqrtf(d) : 0.f;
    cnt[i] = (int)(v >> 32);
    cursor[i] = 0;
  }
}

// ---- 3-kernel scan: block partials -> tops scan -> apply ----
__global__ __launch_bounds__(256) void scan_part(const int* __restrict__ cnt,
    int* __restrict__ part, int n) {
  __shared__ int sb[256];
  int t = threadIdx.x, i = blockIdx.x * 256 + t;
  sb[t] = (i < n) ? cnt[i] : 0;
  __syncthreads();
  for (int off = 128; off > 0; off >>= 1) {
    if (t < off) sb[t] += sb[t + off];
    __syncthreads();
  }
  if (t == 0) part[blockIdx.x] = sb[0];
}

__global__ __launch_bounds__(256) void scan_tops(const int* __restrict__ part,
    int* __restrict__ partoff, int* __restrict__ rowstart, int n, int e, int nb) {
  __shared__ int sb[256];
  int t = threadIdx.x;
  int v = (t < nb) ? part[t] : 0;
  sb[t] = v;
  __syncthreads();
  for (int off = 1; off < 256; off <<= 1) {
    int x = (t >= off) ? sb[t - off] : 0;
    __syncthreads();
    sb[t] += x;
    __syncthreads();
  }
  if (t < nb) partoff[t] = sb[t] - v;   // exclusive block offsets
  if (t == 0) rowstart[n] = e;
}

__global__ __launch_bounds__(256) void scan_apply(const int* __restrict__ cnt,
    const int* __restrict__ partoff, int* __restrict__ rowstart, int n) {
  __shared__ int sb[256];
  int t = threadIdx.x, i = blockIdx.x * 256 + t;
  int v = (i < n) ? cnt[i] : 0;
  sb[t] = v;
  __syncthreads();
  for (int off = 1; off < 256; off <<= 1) {
    int x = (t >= off) ? sb[t - off] : 0;
    __syncthreads();
    sb[t] += x;
    __syncthreads();
  }
  if (i < n) rowstart[i] = partoff[blockIdx.x] + sb[t] - v;
}

// packed edge record: .x = src node, .y = bit-cast norm weight
__global__ __launch_bounds__(256) void prep_scatter(const int* __restrict__ ei,
    const int* __restrict__ flag, const float* __restrict__ ew,
    const float* __restrict__ dis, const int* __restrict__ rowstart,
    int* __restrict__ cursor, int2* __restrict__ epack, int e) {
  int i = blockIdx.x * 256 + threadIdx.x;
  if (i >= e) return;
  int f = *flag;
  int d = get_dst(ei, f, i);
  int s = get_src(ei, f, i);
  int pos = rowstart[d] + atomicAdd(&cursor[d], 1);
  float nm = dis[s] * ew[i] * dis[d];
  epack[pos] = make_int2(s, __float_as_int(nm));
}

// ---------------- input conversions (once) ----------------
__global__ __launch_bounds__(256) void cvt_x(const float* __restrict__ x,
    unsigned short* __restrict__ Hh, unsigned short* __restrict__ Hl,
    int total, int valid) {
  int i = blockIdx.x * 256 + threadIdx.x;
  int b = i * 4;
  if (b >= total) return;
  ushort4 oh, ol;
  float v0 = (b + 0 < valid) ? x[b + 0] : 0.f;
  float v1 = (b + 1 < valid) ? x[b + 1] : 0.f;
  float v2 = (b + 2 < valid) ? x[b + 2] : 0.f;
  float v3 = (b + 3 < valid) ? x[b + 3] : 0.f;
  oh.x = f2b(v0); ol.x = f2b(v0 - b2f(oh.x));
  oh.y = f2b(v1); ol.y = f2b(v1 - b2f(oh.y));
  oh.z = f2b(v2); ol.z = f2b(v2 - b2f(oh.z));
  oh.w = f2b(v3); ol.w = f2b(v3 - b2f(oh.w));
  *(ushort4*)(Hh + b) = oh;
  *(ushort4*)(Hl + b) = ol;
}

// weights [k][n] 128x128 fp32 (7 layers) -> transposed [n][k] hi/lo bf16
__global__ __launch_bounds__(256) void cvt_w(const float* __restrict__ W1,
    const float* __restrict__ Wm, unsigned short* __restrict__ Wth,
    unsigned short* __restrict__ Wtl) {
  int i = blockIdx.x * 256 + threadIdx.x;           // 7*16384
  if (i >= 7 * 16384) return;
  int l = i >> 14, r = i & 16383;
  int k = r >> 7, n = r & 127;
  const float* src = (l == 0) ? W1 : (Wm + (size_t)(l - 1) * 16384);
  float v = src[k * 128 + n];
  unsigned short h = f2b(v);
  int o = l * 16384 + n * 128 + k;
  Wth[o] = h;
  Wtl[o] = f2b(v - b2f(h));
}

// ---------------- MFMA split-bf16 GEMM: XW[MP,128] (fp16) = H @ W ----------------
// 128 rows/block, 32 rows/wave (two 16-row tiles share each B fragment -> 6
// MFMAs per B load). Two-phase LDS-transpose epilogue for coalesced stores.
__global__ __launch_bounds__(256) void gemm_mfma(
    const unsigned short* __restrict__ Hh, const unsigned short* __restrict__ Hl,
    const unsigned short* __restrict__ Bh, const unsigned short* __restrict__ Bl,
    __half* __restrict__ XW) {
  __shared__ float C[64][133];
  int t = threadIdx.x;
  int lane = t & 63, wv = t >> 6;
  int m16 = lane & 15, quad = lane >> 4;
  int rowbase = blockIdx.x * 128;
  int arow0 = rowbase + wv * 32 + m16;
  f32x4 acc0[8], acc1[8];
#pragma unroll
  for (int i = 0; i < 8; ++i) {
    acc0[i] = (f32x4){0.f, 0.f, 0.f, 0.f};
    acc1[i] = (f32x4){0.f, 0.f, 0.f, 0.f};
  }
  const unsigned short* ph0 = Hh + (size_t)arow0 * 128 + quad * 8;
  const unsigned short* pl0 = Hl + (size_t)arow0 * 128 + quad * 8;
#pragma unroll
  for (int kc = 0; kc < 4; ++kc) {
    bf16x8 ah0 = *(const bf16x8*)(ph0 + kc * 32);
    bf16x8 al0 = *(const bf16x8*)(pl0 + kc * 32);
    bf16x8 ah1 = *(const bf16x8*)(ph0 + 16 * 128 + kc * 32);
    bf16x8 al1 = *(const bf16x8*)(pl0 + 16 * 128 + kc * 32);
    int k0 = kc * 32 + quad * 8;
#pragma unroll
    for (int tt = 0; tt < 8; ++tt) {
      int nn = tt * 16 + m16;
      bf16x8 bh = *(const bf16x8*)(Bh + nn * 128 + k0);
      bf16x8 bl = *(const bf16x8*)(Bl + nn * 128 + k0);
      acc0[tt] = __builtin_amdgcn_mfma_f32_16x16x32_bf16(ah0, bh, acc0[tt], 0, 0, 0);
      acc0[tt] = __builtin_amdgcn_mfma_f32_16x16x32_bf16(ah0, bl, acc0[tt], 0, 0, 0);
      acc0[tt] = __builtin_amdgcn_mfma_f32_16x16x32_bf16(al0, bh, acc0[tt], 0, 0, 0);
      acc1[tt] = __builtin_amdgcn_mfma_f32_16x16x32_bf16(ah1, bh, acc1[tt], 0, 0, 0);
      acc1[tt] = __builtin_amdgcn_mfma_f32_16x16x32_bf16(ah1, bl, acc1[tt], 0, 0, 0);
      acc1[tt] = __builtin_amdgcn_mfma_f32_16x16x32_bf16(al1, bh, acc1[tt], 0, 0, 0);
    }
  }
  // epilogue: local C row c maps to global row rowbase + (c>>4)*32 + (c&15) (+16 phase 1)
  int rr = t >> 2;               // 0..63
  int cb = (t & 3) * 32;         // col base
  int grow = rowbase + ((rr >> 4) << 5) + (rr & 15);
#pragma unroll
  for (int ph = 0; ph < 2; ++ph) {
    if (ph) __syncthreads();
#pragma unroll
    for (int tt = 0; tt < 8; ++tt)
#pragma unroll
      for (int r = 0; r < 4; ++r)
        C[wv * 16 + quad * 4 + r][tt * 16 + m16] = ph ? acc1[tt][r] : acc0[tt][r];
    __syncthreads();
    const float* crow = &C[rr][cb];
    __half2 o[16];
#pragma unroll
    for (int i = 0; i < 16; ++i) {
      __half2 h;
      h.x = __float2half_rn(crow[2 * i]);
      h.y = __float2half_rn(crow[2 * i + 1]);
      o[i] = h;
    }
    uint4* dst = (uint4*)(XW + (size_t)(grow + ph * 16) * 128 + cb);
    dst[0] = ((const uint4*)o)[0];
    dst[1] = ((const uint4*)o)[1];
    dst[2] = ((const uint4*)o)[2];
    dst[3] = ((const uint4*)o)[3];
  }
}

// ---------------- CSR aggregation + bias + relu -> bf16 hi/lo H ----------------
// one wave per node; 16-deep fully-predicated unroll (no serial tail).
// Out-of-range slots clamp to (src=w, wt=0) — self row is L1-hot, FMA no-op.
__global__ __launch_bounds__(256) void agg_csr(const __half* __restrict__ XW,
    const int* __restrict__ rowstart, const int2* __restrict__ epack,
    const float* __restrict__ dis, const float* __restrict__ bias,
    unsigned short* __restrict__ Hh, unsigned short* __restrict__ Hl, int n) {
  int w = (blockIdx.x * 256 + threadIdx.x) >> 6;
  int l = threadIdx.x & 63;
  if (w >= n) return;
  float dd = dis[w];
  float d2 = dd * dd;
  __half2 sh = ((const __half2*)(XW + (size_t)w * 128))[l];
  float2 A[8];
  A[0] = make_float2(d2 * __low2float(sh), d2 * __high2float(sh));
#pragma unroll
  for (int i = 1; i < 8; ++i) A[i] = make_float2(0.f, 0.f);
  int p = rowstart[w], p1 = rowstart[w + 1];
  for (; p < p1; p += 16) {
    int idx[16]; int wtb[16];
#pragma unroll
    for (int i = 0; i < 16; ++i) {
      int2 e0 = epack[p + i];              // epack padded +16: safe overread
      bool inb = (p + i < p1);
      idx[i] = inb ? e0.x : w;
      wtb[i] = inb ? e0.y : 0;
    }
    __half2 r[16];
#pragma unroll
    for (int i = 0; i < 16; ++i)
      r[i] = ((const __half2*)(XW + (size_t)idx[i] * 128))[l];
#pragma unroll
    for (int i = 0; i < 16; ++i) {
      float wt = __int_as_float(wtb[i]);
      A[i & 7].x = fmaf(wt, __low2float(r[i]), A[i & 7].x);
      A[i & 7].y = fmaf(wt, __high2float(r[i]), A[i & 7].y);
    }
  }
  float2 b = ((const float2*)bias)[l];
  float vx = fmaxf(A[0].x + A[1].x + A[2].x + A[3].x + A[4].x + A[5].x + A[6].x + A[7].x + b.x, 0.f);
  float vy = fmaxf(A[0].y + A[1].y + A[2].y + A[3].y + A[4].y + A[5].y + A[6].y + A[7].y + b.y, 0.f);
  ushort2 oh, ol;
  oh.x = f2b(vx); ol.x = f2b(vx - b2f(oh.x));
  oh.y = f2b(vy); ol.y = f2b(vy - b2f(oh.y));
  ((ushort2*)(Hh + (size_t)w * 128))[l] = oh;
  ((ushort2*)(Hl + (size_t)w * 128))[l] = ol;
}

// ---------------- final layer ----------------
__global__ __launch_bounds__(256) void gemm_w8(const unsigned short* __restrict__ Hh,
    const unsigned short* __restrict__ Hl, const float* __restrict__ W8,
    float* __restrict__ XW2, int n) {
  __shared__ float w[256];
  int t = threadIdx.x;
  w[t] = W8[t];
  __syncthreads();
  int r = blockIdx.x * 256 + t;
  if (r >= n) return;
  const unsigned short* hh = Hh + (size_t)r * 128;
  const unsigned short* hl = Hl + (size_t)r * 128;
  float a0 = 0.f, a1 = 0.f;
#pragma unroll
  for (int k = 0; k < 128; k += 4) {
    ushort4 uh = *(const ushort4*)(hh + k);
    ushort4 ul = *(const ushort4*)(hl + k);
    float h0 = b2f(uh.x) + b2f(ul.x);
    float h1 = b2f(uh.y) + b2f(ul.y);
    float h2 = b2f(uh.z) + b2f(ul.z);
    float h3 = b2f(uh.w) + b2f(ul.w);
    a0 += h0 * w[2 * k + 0] + h1 * w[2 * k + 2] + h2 * w[2 * k + 4] + h3 * w[2 * k + 6];
    a1 += h0 * w[2 * k + 1] + h1 * w[2 * k + 3] + h2 * w[2 * k + 5] + h3 * w[2 * k + 7];
  }
  XW2[r * 2 + 0] = a0;
  XW2[r * 2 + 1] = a1;
}

__global__ __launch_bounds__(256) void agg_final(const float* __restrict__ XW2,
    const int* __restrict__ rowstart, const int2* __restrict__ epack,
    const float* __restrict__ dis, const float* __restrict__ b8,
    float* __restrict__ out, int n) {
  int i = blockIdx.x * 256 + threadIdx.x;
  if (i >= n) return;
  float d = dis[i], d2 = d * d;
  float a0 = d2 * XW2[i * 2 + 0];
  float a1 = d2 * XW2[i * 2 + 1];
  int p1 = rowstart[i + 1];
  for (int p = rowstart[i]; p < p1; ++p) {
    int2 e0 = epack[p];
    float wt = __int_as_float(e0.y);
    a0 = fmaf(wt, XW2[e0.x * 2 + 0], a0);
    a1 = fmaf(wt, XW2[e0.x * 2 + 1], a1);
  }
  out[i * 2 + 0] = a0 + b8[0];
  out[i * 2 + 1] = a1 + b8[1];
}

// ---------------- launcher ----------------
static inline char* alignp(char* p) {
  return (char*)(((uintptr_t)p + 255) & ~(uintptr_t)255);
}

extern "C" void kernel_launch(void* const* d_in, const int* in_sizes, int n_in,
                              void* d_out, int out_size, void* d_ws, size_t ws_size,
                              hipStream_t stream) {
  (void)in_sizes; (void)n_in; (void)out_size; (void)ws_size;
  const int n = NN, e = NE;
  const float* x  = (const float*)d_in[0];
  const int*   ei = (const int*)d_in[1];
  const float* ea = (const float*)d_in[2];
  const float* W1 = (const float*)d_in[3];
  const float* b1 = (const float*)d_in[4];
  const float* Wm = (const float*)d_in[5];
  const float* bm = (const float*)d_in[6];
  const float* W8 = (const float*)d_in[7];
  const float* b8 = (const float*)d_in[8];
  float* out = (float*)d_out;

  char* w = (char*)d_ws;
  int*   flag   = (int*)w;            w = alignp(w + 4);
  int*   part   = (int*)w;            w = alignp(w + SCAN_NB * 4);
  int*   partoff= (int*)w;            w = alignp(w + SCAN_NB * 4);
  unsigned long long* dc = (unsigned long long*)w; w = alignp(w + (size_t)n * 8);
  float* dis    = (float*)w;          w = alignp(w + (size_t)n * 4);
  int*   cnt    = (int*)w;            w = alignp(w + (size_t)n * 4);
  int*   cursor = (int*)w;            w = alignp(w + (size_t)n * 4);
  int*   rowst  = (int*)w;            w = alignp(w + (size_t)(n + 1) * 4);
  int2*  epack  = (int2*)w;           w = alignp(w + (size_t)(e + 16) * 8);
  unsigned short* Hh  = (unsigned short*)w;  w = alignp(w + (size_t)MP * 128 * 2);
  unsigned short* Hl  = (unsigned short*)w;  w = alignp(w + (size_t)MP * 128 * 2);
  unsigned short* Wth = (unsigned short*)w;  w = alignp(w + (size_t)7 * 16384 * 2);
  unsigned short* Wtl = (unsigned short*)w;  w = alignp(w + (size_t)7 * 16384 * 2);
  __half* XW  = (__half*)w;           w = alignp(w + (size_t)MP * 128 * 2);
  float* XW2  = (float*)w;            w = alignp(w + (size_t)MP * 2 * 4);

  const int GN = (n + 255) / 256;
  const int GE = (e + 255) / 256;

  detect_idx<<<1, 64, 0, stream>>>(ei, flag);
  prep_init<<<GN, 256, 0, stream>>>(dc, n);
  prep_hist<<<GE, 256, 0, stream>>>(ei, flag, ea, dc, e);
  prep_dis<<<GN, 256, 0, stream>>>(dc, dis, cnt, cursor, n);
  scan_part<<<SCAN_NB, 256, 0, stream>>>(cnt, part, n);
  scan_tops<<<1, 256, 0, stream>>>(part, partoff, rowst, n, e, SCAN_NB);
  scan_apply<<<SCAN_NB, 256, 0, stream>>>(cnt, partoff, rowst, n);
  prep_scatter<<<GE, 256, 0, stream>>>(ei, flag, ea, dis, rowst, cursor, epack, e);
  cvt_x<<<(MP * 128 / 4 + 255) / 256, 256, 0, stream>>>(x, Hh, Hl, MP * 128, n * 128);
  cvt_w<<<(7 * 16384 + 255) / 256, 256, 0, stream>>>(W1, Wm, Wth, Wtl);

  for (int l = 0; l < 7; ++l) {
    const unsigned short* Bh = Wth + (size_t)l * 16384;
    const unsigned short* Bl = Wtl + (size_t)l * 16384;
    const float* bl = (l == 0) ? b1 : bm + (size_t)(l - 1) * 128;
    gemm_mfma<<<MP / 128, 256, 0, stream>>>(Hh, Hl, Bh, Bl, XW);
    agg_csr<<<(n * 64 + 255) / 256, 256, 0, stream>>>(XW, rowst, epack, dis, bl, Hh, Hl, n);
  }
  gemm_w8<<<GN, 256, 0, stream>>>(Hh, Hl, W8, XW2, n);
  agg_final<<<GN, 256, 0, stream>>>(XW2, rowst, epack, dis, b8, out, n);
}

// Round 8
// 604.473 us; speedup vs baseline: 1.2946x; 1.0473x over previous
//
#include <hip/hip_runtime.h>
#include <hip/hip_bf16.h>
#include <hip/hip_fp16.h>

#define NN 50000
#define NE 800000
#define MP 50048            // NN padded to multiple of 128
#define SCAN_NB 196         // ceil(NN/256)
#define CVT_XB 6256         // MP*128/4/256 blocks for x conversion
#define CVT_WB 448          // 7*16384/256 blocks for w conversion

typedef __bf16 bf16x8 __attribute__((ext_vector_type(8)));
typedef float f32x4 __attribute__((ext_vector_type(4)));

static __device__ __forceinline__ float b2f(unsigned short u) {
  union { unsigned int i; float f; } v; v.i = ((unsigned int)u) << 16; return v.f;
}
static __device__ __forceinline__ unsigned short f2b(float f) {
  __hip_bfloat16 h = __float2bfloat16(f);
  union { __hip_bfloat16 h; unsigned short u; } v; v.h = h; return v.u;
}
static __device__ __forceinline__ float h2f_bits(unsigned short u) {
  __half h; union { __half h; unsigned short u; } v; v.u = u; h = v.h;
  return __half2float(h);
}
static __device__ __forceinline__ unsigned short f2h_bits(float f) {
  union { __half h; unsigned short u; } v; v.h = __float2half_rn(f); return v.u;
}

// ---------------- fused: detect edge-index width + init dc ----------------
// dc[i]: high 32 = edge count, low 32 = fixed-point (2^-20) weighted degree
__global__ __launch_bounds__(256) void prep_init(const int* __restrict__ ei,
    int* flag, unsigned long long* dc, int n) {
  int i = blockIdx.x * 256 + threadIdx.x;
  if (i < n) dc[i] = 1048576ull;   // self-loop weight 1.0, cnt 0
  if (blockIdx.x == 0 && threadIdx.x < 64) {
    __shared__ int nz;
    if (threadIdx.x == 0) nz = 0;
    __syncthreads();
    if (ei[2 * threadIdx.x + 1] != 0) atomicAdd(&nz, 1);
    __syncthreads();
    if (threadIdx.x == 0) *flag = (nz == 0) ? 1 : 0;   // 1 => int64 layout
  }
}

static __device__ __forceinline__ int get_src(const int* ei, int f, int i) {
  return f ? ei[2 * i] : ei[i];
}
static __device__ __forceinline__ int get_dst(const int* ei, int f, int i) {
  return f ? ei[2 * (NE + i)] : ei[NE + i];
}

__global__ __launch_bounds__(256) void prep_hist(const int* __restrict__ ei,
    const int* __restrict__ flag, const float* __restrict__ ew,
    unsigned long long* dc, int e) {
  int i = blockIdx.x * 256 + threadIdx.x;
  if (i < e) {
    int f = *flag;
    int d = get_dst(ei, f, i);
    unsigned long long fx = (unsigned long long)(ew[i] * 1048576.0f + 0.5f);
    atomicAdd(&dc[d], (1ull << 32) | fx);
  }
}

// fused: dis/cnt/cursor compute + per-block cnt partial sum
__global__ __launch_bounds__(256) void prep_dis_part(
    const unsigned long long* __restrict__ dc, float* dis, int* cnt,
    int* cursor, int* __restrict__ part, int n) {
  __shared__ int sb[256];
  int t = threadIdx.x, i = blockIdx.x * 256 + t;
  int c = 0;
  if (i < n) {
    unsigned long long v = dc[i];
    float d = (float)(unsigned int)(v & 0xffffffffull) * (1.0f / 1048576.0f);
    dis[i] = (d > 0.f) ? rsqrtf(d) : 0.f;
    c = (int)(v >> 32);
    cnt[i] = c;
    cursor[i] = 0;
  }
  sb[t] = c;
  __syncthreads();
  for (int off = 128; off > 0; off >>= 1) {
    if (t < off) sb[t] += sb[t + off];
    __syncthreads();
  }
  if (t == 0) part[blockIdx.x] = sb[0];
}

__global__ __launch_bounds__(256) void scan_tops(const int* __restrict__ part,
    int* __restrict__ partoff, int* __restrict__ rowstart, int n, int e, int nb) {
  __shared__ int sb[256];
  int t = threadIdx.x;
  int v = (t < nb) ? part[t] : 0;
  sb[t] = v;
  __syncthreads();
  for (int off = 1; off < 256; off <<= 1) {
    int x = (t >= off) ? sb[t - off] : 0;
    __syncthreads();
    sb[t] += x;
    __syncthreads();
  }
  if (t < nb) partoff[t] = sb[t] - v;   // exclusive block offsets
  if (t == 0) rowstart[n] = e;
}

__global__ __launch_bounds__(256) void scan_apply(const int* __restrict__ cnt,
    const int* __restrict__ partoff, int* __restrict__ rowstart, int n) {
  __shared__ int sb[256];
  int t = threadIdx.x, i = blockIdx.x * 256 + t;
  int v = (i < n) ? cnt[i] : 0;
  sb[t] = v;
  __syncthreads();
  for (int off = 1; off < 256; off <<= 1) {
    int x = (t >= off) ? sb[t - off] : 0;
    __syncthreads();
    sb[t] += x;
    __syncthreads();
  }
  if (i < n) rowstart[i] = partoff[blockIdx.x] + sb[t] - v;
}

// packed 4B edge record: low16 = src node (N<65536), high16 = fp16 norm bits
__global__ __launch_bounds__(256) void prep_scatter(const int* __restrict__ ei,
    const int* __restrict__ flag, const float* __restrict__ ew,
    const float* __restrict__ dis, const int* __restrict__ rowstart,
    int* __restrict__ cursor, unsigned int* __restrict__ epack, int e) {
  int i = blockIdx.x * 256 + threadIdx.x;
  if (i >= e) return;
  int f = *flag;
  int d = get_dst(ei, f, i);
  int s = get_src(ei, f, i);
  int pos = rowstart[d] + atomicAdd(&cursor[d], 1);
  float nm = dis[s] * ew[i] * dis[d];
  unsigned int rec = (unsigned int)s | ((unsigned int)f2h_bits(nm) << 16);
  __builtin_nontemporal_store(rec, epack + pos);
}

// ---------------- fused input conversions (once) ----------------
__global__ __launch_bounds__(256) void cvt_xw(const float* __restrict__ x,
    unsigned short* __restrict__ Hh, unsigned short* __restrict__ Hl,
    const float* __restrict__ W1, const float* __restrict__ Wm,
    unsigned short* __restrict__ Wth, unsigned short* __restrict__ Wtl,
    int valid) {
  if (blockIdx.x < CVT_XB) {
    int b = (blockIdx.x * 256 + threadIdx.x) * 4;
    ushort4 oh, ol;
    float v0 = (b + 0 < valid) ? x[b + 0] : 0.f;
    float v1 = (b + 1 < valid) ? x[b + 1] : 0.f;
    float v2 = (b + 2 < valid) ? x[b + 2] : 0.f;
    float v3 = (b + 3 < valid) ? x[b + 3] : 0.f;
    oh.x = f2b(v0); ol.x = f2b(v0 - b2f(oh.x));
    oh.y = f2b(v1); ol.y = f2b(v1 - b2f(oh.y));
    oh.z = f2b(v2); ol.z = f2b(v2 - b2f(oh.z));
    oh.w = f2b(v3); ol.w = f2b(v3 - b2f(oh.w));
    *(ushort4*)(Hh + b) = oh;
    *(ushort4*)(Hl + b) = ol;
  } else {
    int i = (blockIdx.x - CVT_XB) * 256 + threadIdx.x;   // 7*16384
    int l = i >> 14, r = i & 16383;
    int k = r >> 7, n = r & 127;
    const float* src = (l == 0) ? W1 : (Wm + (size_t)(l - 1) * 16384);
    float v = src[k * 128 + n];
    unsigned short h = f2b(v);
    int o = l * 16384 + n * 128 + k;
    Wth[o] = h;
    Wtl[o] = f2b(v - b2f(h));
  }
}

// ---------------- MFMA split-bf16 GEMM: XW[MP,128] (fp16) = H @ W ----------------
// 128 rows/block, 32 rows/wave (two 16-row tiles share each B fragment -> 6
// MFMAs per B load). Two-phase LDS-transpose epilogue for coalesced stores.
__global__ __launch_bounds__(256) void gemm_mfma(
    const unsigned short* __restrict__ Hh, const unsigned short* __restrict__ Hl,
    const unsigned short* __restrict__ Bh, const unsigned short* __restrict__ Bl,
    __half* __restrict__ XW) {
  __shared__ float C[64][133];
  int t = threadIdx.x;
  int lane = t & 63, wv = t >> 6;
  int m16 = lane & 15, quad = lane >> 4;
  int rowbase = blockIdx.x * 128;
  int arow0 = rowbase + wv * 32 + m16;
  f32x4 acc0[8], acc1[8];
#pragma unroll
  for (int i = 0; i < 8; ++i) {
    acc0[i] = (f32x4){0.f, 0.f, 0.f, 0.f};
    acc1[i] = (f32x4){0.f, 0.f, 0.f, 0.f};
  }
  const unsigned short* ph0 = Hh + (size_t)arow0 * 128 + quad * 8;
  const unsigned short* pl0 = Hl + (size_t)arow0 * 128 + quad * 8;
#pragma unroll
  for (int kc = 0; kc < 4; ++kc) {
    bf16x8 ah0 = *(const bf16x8*)(ph0 + kc * 32);
    bf16x8 al0 = *(const bf16x8*)(pl0 + kc * 32);
    bf16x8 ah1 = *(const bf16x8*)(ph0 + 16 * 128 + kc * 32);
    bf16x8 al1 = *(const bf16x8*)(pl0 + 16 * 128 + kc * 32);
    int k0 = kc * 32 + quad * 8;
#pragma unroll
    for (int tt = 0; tt < 8; ++tt) {
      int nn = tt * 16 + m16;
      bf16x8 bh = *(const bf16x8*)(Bh + nn * 128 + k0);
      bf16x8 bl = *(const bf16x8*)(Bl + nn * 128 + k0);
      acc0[tt] = __builtin_amdgcn_mfma_f32_16x16x32_bf16(ah0, bh, acc0[tt], 0, 0, 0);
      acc0[tt] = __builtin_amdgcn_mfma_f32_16x16x32_bf16(ah0, bl, acc0[tt], 0, 0, 0);
      acc0[tt] = __builtin_amdgcn_mfma_f32_16x16x32_bf16(al0, bh, acc0[tt], 0, 0, 0);
      acc1[tt] = __builtin_amdgcn_mfma_f32_16x16x32_bf16(ah1, bh, acc1[tt], 0, 0, 0);
      acc1[tt] = __builtin_amdgcn_mfma_f32_16x16x32_bf16(ah1, bl, acc1[tt], 0, 0, 0);
      acc1[tt] = __builtin_amdgcn_mfma_f32_16x16x32_bf16(al1, bh, acc1[tt], 0, 0, 0);
    }
  }
  int rr = t >> 2;               // 0..63
  int cb = (t & 3) * 32;         // col base
  int grow = rowbase + ((rr >> 4) << 5) + (rr & 15);
#pragma unroll
  for (int ph = 0; ph < 2; ++ph) {
    if (ph) __syncthreads();
#pragma unroll
    for (int tt = 0; tt < 8; ++tt)
#pragma unroll
      for (int r = 0; r < 4; ++r)
        C[wv * 16 + quad * 4 + r][tt * 16 + m16] = ph ? acc1[tt][r] : acc0[tt][r];
    __syncthreads();
    const float* crow = &C[rr][cb];
    __half2 o[16];
#pragma unroll
    for (int i = 0; i < 16; ++i) {
      __half2 h;
      h.x = __float2half_rn(crow[2 * i]);
      h.y = __float2half_rn(crow[2 * i + 1]);
      o[i] = h;
    }
    uint4* dst = (uint4*)(XW + (size_t)(grow + ph * 16) * 128 + cb);
    dst[0] = ((const uint4*)o)[0];
    dst[1] = ((const uint4*)o)[1];
    dst[2] = ((const uint4*)o)[2];
    dst[3] = ((const uint4*)o)[3];
  }
}

// ---------------- CSR aggregation + bias + relu -> bf16 hi/lo H ----------------
// one wave per node; 16-deep fully-predicated unroll (no serial tail).
__global__ __launch_bounds__(256) void agg_csr(const __half* __restrict__ XW,
    const int* __restrict__ rowstart, const unsigned int* __restrict__ epack,
    const float* __restrict__ dis, const float* __restrict__ bias,
    unsigned short* __restrict__ Hh, unsigned short* __restrict__ Hl, int n) {
  int w = (blockIdx.x * 256 + threadIdx.x) >> 6;
  int l = threadIdx.x & 63;
  if (w >= n) return;
  float dd = dis[w];
  float d2 = dd * dd;
  __half2 sh = ((const __half2*)(XW + (size_t)w * 128))[l];
  float2 A[8];
  A[0] = make_float2(d2 * __low2float(sh), d2 * __high2float(sh));
#pragma unroll
  for (int i = 1; i < 8; ++i) A[i] = make_float2(0.f, 0.f);
  int p = rowstart[w], p1 = rowstart[w + 1];
  for (; p < p1; p += 16) {
    int idx[16]; unsigned short wtb[16];
#pragma unroll
    for (int i = 0; i < 16; ++i) {
      unsigned int rec = epack[p + i];     // epack padded +16: safe overread
      bool inb = (p + i < p1);
      idx[i] = inb ? (int)(rec & 0xffffu) : w;
      wtb[i] = inb ? (unsigned short)(rec >> 16) : (unsigned short)0;
    }
    __half2 r[16];
#pragma unroll
    for (int i = 0; i < 16; ++i)
      r[i] = ((const __half2*)(XW + (size_t)idx[i] * 128))[l];
#pragma unroll
    for (int i = 0; i < 16; ++i) {
      float wt = h2f_bits(wtb[i]);
      A[i & 7].x = fmaf(wt, __low2float(r[i]), A[i & 7].x);
      A[i & 7].y = fmaf(wt, __high2float(r[i]), A[i & 7].y);
    }
  }
  float2 b = ((const float2*)bias)[l];
  float vx = fmaxf(A[0].x + A[1].x + A[2].x + A[3].x + A[4].x + A[5].x + A[6].x + A[7].x + b.x, 0.f);
  float vy = fmaxf(A[0].y + A[1].y + A[2].y + A[3].y + A[4].y + A[5].y + A[6].y + A[7].y + b.y, 0.f);
  ushort2 oh, ol;
  oh.x = f2b(vx); ol.x = f2b(vx - b2f(oh.x));
  oh.y = f2b(vy); ol.y = f2b(vy - b2f(oh.y));
  ((ushort2*)(Hh + (size_t)w * 128))[l] = oh;
  ((ushort2*)(Hl + (size_t)w * 128))[l] = ol;
}

// ---------------- final layer ----------------
__global__ __launch_bounds__(256) void gemm_w8(const unsigned short* __restrict__ Hh,
    const unsigned short* __restrict__ Hl, const float* __restrict__ W8,
    float* __restrict__ XW2, int n) {
  __shared__ float w[256];
  int t = threadIdx.x;
  w[t] = W8[t];
  __syncthreads();
  int r = blockIdx.x * 256 + t;
  if (r >= n) return;
  const unsigned short* hh = Hh + (size_t)r * 128;
  const unsigned short* hl = Hl + (size_t)r * 128;
  float a0 = 0.f, a1 = 0.f;
#pragma unroll
  for (int k = 0; k < 128; k += 4) {
    ushort4 uh = *(const ushort4*)(hh + k);
    ushort4 ul = *(const ushort4*)(hl + k);
    float h0 = b2f(uh.x) + b2f(ul.x);
    float h1 = b2f(uh.y) + b2f(ul.y);
    float h2 = b2f(uh.z) + b2f(ul.z);
    float h3 = b2f(uh.w) + b2f(ul.w);
    a0 += h0 * w[2 * k + 0] + h1 * w[2 * k + 2] + h2 * w[2 * k + 4] + h3 * w[2 * k + 6];
    a1 += h0 * w[2 * k + 1] + h1 * w[2 * k + 3] + h2 * w[2 * k + 5] + h3 * w[2 * k + 7];
  }
  XW2[r * 2 + 0] = a0;
  XW2[r * 2 + 1] = a1;
}

__global__ __launch_bounds__(256) void agg_final(const float* __restrict__ XW2,
    const int* __restrict__ rowstart, const unsigned int* __restrict__ epack,
    const float* __restrict__ dis, const float* __restrict__ b8,
    float* __restrict__ out, int n) {
  int i = blockIdx.x * 256 + threadIdx.x;
  if (i >= n) return;
  float d = dis[i], d2 = d * d;
  float a0 = d2 * XW2[i * 2 + 0];
  float a1 = d2 * XW2[i * 2 + 1];
  int p1 = rowstart[i + 1];
  for (int p = rowstart[i]; p < p1; ++p) {
    unsigned int rec = epack[p];
    int s = (int)(rec & 0xffffu);
    float wt = h2f_bits((unsigned short)(rec >> 16));
    a0 = fmaf(wt, XW2[s * 2 + 0], a0);
    a1 = fmaf(wt, XW2[s * 2 + 1], a1);
  }
  out[i * 2 + 0] = a0 + b8[0];
  out[i * 2 + 1] = a1 + b8[1];
}

// ---------------- launcher ----------------
static inline char* alignp(char* p) {
  return (char*)(((uintptr_t)p + 255) & ~(uintptr_t)255);
}

extern "C" void kernel_launch(void* const* d_in, const int* in_sizes, int n_in,
                              void* d_out, int out_size, void* d_ws, size_t ws_size,
                              hipStream_t stream) {
  (void)in_sizes; (void)n_in; (void)out_size; (void)ws_size;
  const int n = NN, e = NE;
  const float* x  = (const float*)d_in[0];
  const int*   ei = (const int*)d_in[1];
  const float* ea = (const float*)d_in[2];
  const float* W1 = (const float*)d_in[3];
  const float* b1 = (const float*)d_in[4];
  const float* Wm = (const float*)d_in[5];
  const float* bm = (const float*)d_in[6];
  const float* W8 = (const float*)d_in[7];
  const float* b8 = (const float*)d_in[8];
  float* out = (float*)d_out;

  char* w = (char*)d_ws;
  int*   flag   = (int*)w;            w = alignp(w + 4);
  int*   part   = (int*)w;            w = alignp(w + SCAN_NB * 4);
  int*   partoff= (int*)w;            w = alignp(w + SCAN_NB * 4);
  unsigned long long* dc = (unsigned long long*)w; w = alignp(w + (size_t)n * 8);
  float* dis    = (float*)w;          w = alignp(w + (size_t)n * 4);
  int*   cnt    = (int*)w;            w = alignp(w + (size_t)n * 4);
  int*   cursor = (int*)w;            w = alignp(w + (size_t)n * 4);
  int*   rowst  = (int*)w;            w = alignp(w + (size_t)(n + 1) * 4);
  unsigned int* epack = (unsigned int*)w;    w = alignp(w + (size_t)(e + 16) * 4);
  unsigned short* Hh  = (unsigned short*)w;  w = alignp(w + (size_t)MP * 128 * 2);
  unsigned short* Hl  = (unsigned short*)w;  w = alignp(w + (size_t)MP * 128 * 2);
  unsigned short* Wth = (unsigned short*)w;  w = alignp(w + (size_t)7 * 16384 * 2);
  unsigned short* Wtl = (unsigned short*)w;  w = alignp(w + (size_t)7 * 16384 * 2);
  __half* XW  = (__half*)w;           w = alignp(w + (size_t)MP * 128 * 2);
  float* XW2  = (float*)w;            w = alignp(w + (size_t)MP * 2 * 4);

  const int GN = (n + 255) / 256;
  const int GE = (e + 255) / 256;

  prep_init<<<GN, 256, 0, stream>>>(ei, flag, dc, n);
  prep_hist<<<GE, 256, 0, stream>>>(ei, flag, ea, dc, e);
  prep_dis_part<<<SCAN_NB, 256, 0, stream>>>(dc, dis, cnt, cursor, part, n);
  scan_tops<<<1, 256, 0, stream>>>(part, partoff, rowst, n, e, SCAN_NB);
  scan_apply<<<SCAN_NB, 256, 0, stream>>>(cnt, partoff, rowst, n);
  prep_scatter<<<GE, 256, 0, stream>>>(ei, flag, ea, dis, rowst, cursor, epack, e);
  cvt_xw<<<CVT_XB + CVT_WB, 256, 0, stream>>>(x, Hh, Hl, W1, Wm, Wth, Wtl, n * 128);

  for (int l = 0; l < 7; ++l) {
    const unsigned short* Bh = Wth + (size_t)l * 16384;
    const unsigned short* Bl = Wtl + (size_t)l * 16384;
    const float* bl = (l == 0) ? b1 : bm + (size_t)(l - 1) * 128;
    gemm_mfma<<<MP / 128, 256, 0, stream>>>(Hh, Hl, Bh, Bl, XW);
    agg_csr<<<(n * 64 + 255) / 256, 256, 0, stream>>>(XW, rowst, epack, dis, bl, Hh, Hl, n);
  }
  gemm_w8<<<GN, 256, 0, stream>>>(Hh, Hl, W8, XW2, n);
  agg_final<<<GN, 256, 0, stream>>>(XW2, rowst, epack, dis, b8, out, n);
}